// Round 1
// baseline (168.289 us; speedup 1.0000x reference)
//
#include <hip/hip_runtime.h>

// MinimalAdderNN: base-10 ripple-carry adder, one-hot output [BATCH, 11, 10] f32.
// Tables are deterministic -> replaced by arithmetic. Memory-bound on the
// 461 MB one-hot output write; write it coalesced via cooperative float4 stores.

#define ROWS_PER_BLOCK 256
#define THREADS 256
#define FLOATS_PER_ROW 110  // 11 positions * 10 slots

__global__ __launch_bounds__(THREADS) void adder_onehot_kernel(
    const int* __restrict__ a, const int* __restrict__ b,
    float* __restrict__ out, int batch) {
    __shared__ int digits[ROWS_PER_BLOCK][12];  // 11 used (+1 pad); digit value 0..9 per position

    const int t = threadIdx.x;
    const int row0 = blockIdx.x * ROWS_PER_BLOCK;
    const int row = row0 + t;

    // ---- Phase 1: per-row carry chain -> LDS ----
    if (row < batch) {
        const int* ap = a + (size_t)row * 10;
        const int* bp = b + (size_t)row * 10;
        int av[10], bv[10];
#pragma unroll
        for (int p = 0; p < 10; ++p) av[p] = ap[p];
#pragma unroll
        for (int p = 0; p < 10; ++p) bv[p] = bp[p];

        int carry = 0;
#pragma unroll
        for (int p = 9; p >= 0; --p) {  // LSD first
            int total = av[p] + bv[p] + carry;
            int c = total >= 10;
            digits[t][1 + p] = total - (c ? 10 : 0);
            carry = c;
        }
        digits[t][0] = carry;  // leading one-hot position = final carry (0 or 1)
    }
    __syncthreads();

    // ---- Phase 2: cooperative coalesced one-hot write ----
    // Block's output region: rows [row0, row0+256) -> contiguous 256*110 floats.
    const int rows_here = min(ROWS_PER_BLOCK, batch - row0);
    const int total_f = rows_here * FLOATS_PER_ROW;
    float* outb = out + (size_t)row0 * FLOATS_PER_ROW;

    for (int i = t * 4; i < total_f; i += THREADS * 4) {
        float4 v;
        float* vp = &v.x;
#pragma unroll
        for (int k = 0; k < 4; ++k) {
            int idx = i + k;
            int rl = idx / FLOATS_PER_ROW;          // local row
            int rem = idx - rl * FLOATS_PER_ROW;
            int pos = rem / 10;                      // 0..10
            int slot = rem - pos * 10;               // 0..9
            vp[k] = (digits[rl][pos] == slot) ? 1.0f : 0.0f;
        }
        *(float4*)(outb + i) = v;  // 16B-aligned: i is a multiple of 4 floats
    }
}

extern "C" void kernel_launch(void* const* d_in, const int* in_sizes, int n_in,
                              void* d_out, int out_size, void* d_ws, size_t ws_size,
                              hipStream_t stream) {
    const int* a = (const int*)d_in[0];
    const int* b = (const int*)d_in[1];
    // d_in[2] (digit_table) and d_in[3] (carry_table) are deterministic -> unused.
    float* out = (float*)d_out;
    const int batch = in_sizes[0] / 10;

    const int grid = (batch + ROWS_PER_BLOCK - 1) / ROWS_PER_BLOCK;
    adder_onehot_kernel<<<grid, THREADS, 0, stream>>>(a, b, out, batch);
}

// Round 2
// 112.569 us; speedup vs baseline: 1.4950x; 1.4950x over previous
//
#include <hip/hip_runtime.h>

// MinimalAdderNN: base-10 ripple-carry adder -> one-hot logits [BATCH, 11, 10] f32.
// Tables replaced by arithmetic. Strategy: build each row's 440B one-hot image
// in LDS (zero + 11 scattered 1.0f writes), then stream LDS->global with pure
// float4 copies (no per-element math) to run at the HBM write ceiling.

#define ROWS 128               // rows per block
#define THREADS 256
#define FPR 110                // floats per row: 11 positions * 10 slots
#define LDS_FLOATS (ROWS * FPR)   // 14080 floats = 56320 B
#define LDS_VEC4 (LDS_FLOATS / 4) // 3520 float4s

__global__ __launch_bounds__(THREADS) void adder_onehot_kernel(
    const int* __restrict__ a, const int* __restrict__ b,
    float* __restrict__ out, int batch) {
    __shared__ __align__(16) float buf[LDS_FLOATS];

    const int t = threadIdx.x;
    const int row0 = blockIdx.x * ROWS;

    // ---- Phase 0: zero the LDS image (ds_write_b128, conflict-free) ----
    float4* buf4 = (float4*)buf;
    const float4 z = make_float4(0.f, 0.f, 0.f, 0.f);
    for (int i = t; i < LDS_VEC4; i += THREADS) buf4[i] = z;

    // ---- Phase 1: threads 0..127 compute their row's digits ----
    int dig[11];
    const bool active = (t < ROWS) && (row0 + t < batch);
    if (active) {
        const int* ap = a + (size_t)(row0 + t) * 10;
        const int* bp = b + (size_t)(row0 + t) * 10;
        int av[10], bv[10];
#pragma unroll
        for (int p = 0; p < 10; ++p) av[p] = ap[p];
#pragma unroll
        for (int p = 0; p < 10; ++p) bv[p] = bp[p];
        int carry = 0;
#pragma unroll
        for (int p = 9; p >= 0; --p) {  // LSD first
            int tot = av[p] + bv[p] + carry;
            int c = tot >= 10;
            dig[1 + p] = c ? tot - 10 : tot;
            carry = c;
        }
        dig[0] = carry;  // leading one-hot position = final carry
    }
    __syncthreads();  // zeroing complete before scatter

    if (active) {
        float* rb = buf + t * FPR;  // row stride 110 words -> <=4-way bank alias, cheap
#pragma unroll
        for (int pos = 0; pos < 11; ++pos)
            rb[pos * 10 + dig[pos]] = 1.0f;
    }
    __syncthreads();  // image complete before copy

    // ---- Phase 2: pure coalesced LDS -> global float4 copy ----
    const int rows_here = min(ROWS, batch - row0);
    const int total_f = rows_here * FPR;
    const int nvec = total_f / 4;  // full block: 3520 (exact)
    float4* out4 = (float4*)(out + (size_t)row0 * FPR);  // base: row0*440B, 16B-aligned (row0 % 4 == 0)
    for (int i = t; i < nvec; i += THREADS) out4[i] = buf4[i];

    // scalar tail (only possible for a ragged last block; batch=2^20 -> none)
    const int tail0 = nvec * 4;
    if (t < total_f - tail0)
        out[(size_t)row0 * FPR + tail0 + t] = buf[tail0 + t];
}

extern "C" void kernel_launch(void* const* d_in, const int* in_sizes, int n_in,
                              void* d_out, int out_size, void* d_ws, size_t ws_size,
                              hipStream_t stream) {
    const int* a = (const int*)d_in[0];
    const int* b = (const int*)d_in[1];
    // d_in[2]/d_in[3] (lookup tables) are deterministic -> replaced by arithmetic.
    float* out = (float*)d_out;
    const int batch = in_sizes[0] / 10;

    const int grid = (batch + ROWS - 1) / ROWS;
    adder_onehot_kernel<<<grid, THREADS, 0, stream>>>(a, b, out, batch);
}